// Round 3
// baseline (307.032 us; speedup 1.0000x reference)
//
#include <hip/hip_runtime.h>

typedef short short8 __attribute__((ext_vector_type(8)));
typedef float floatx4 __attribute__((ext_vector_type(4)));

#define TDIM 6
#define XDIM 24
#define YDIM 24
#define ZDIM 12
#define VOL 41472   // 6*24*24*12
#define EPSV 1e-5f
#define SLOPE 0.1f

// Padded activation layout: [t][x][py=28][pz=16][32ch] bf16, halo zeros.
// pv(t,x,y,z) = ((t*24+x)*28 + y+2)*16 + z+2 ; elem = pv*32 + c
#define NPV 64512           // 6*24*28*16
// workspace byte offsets
#define ACT_OFF   0u        // 4,128,768 B used; 4 MiB region zeroed (slack)
#define CONV_OFF  4194304u  // VOL*32*4 = 5,308,416 B fp32
#define WB_OFF    9502720u  // up to 768,000 B bf16 frags
#define STATS_OFF 10270720u // 512 B
#define PART_OFF  10271232u // 65,536 B

__device__ inline unsigned short f2bf(float f) {
  unsigned u = __builtin_bit_cast(unsigned, f);
  unsigned r = u + 0x7fffu + ((u >> 16) & 1u);
  return (unsigned short)(r >> 16);
}
__device__ inline float bf2f(unsigned short h) {
  unsigned u = ((unsigned)h) << 16;
  return __builtin_bit_cast(float, u);
}

__global__ __launch_bounds__(256) void zero_act(float4* __restrict__ p) {
  p[blockIdx.x * 256 + threadIdx.x] = make_float4(0.f, 0.f, 0.f, 0.f);
}

// ---------------- embed -> padded bf16 act --------------------------------
__global__ __launch_bounds__(256) void embed_kernel(
    const float* __restrict__ x, const float* __restrict__ w,
    const float* __restrict__ b, unsigned short* __restrict__ act) {
  int v = blockIdx.x * 256 + threadIdx.x;
  const float4* xp = reinterpret_cast<const float4*>(x + (size_t)v * 8);
  float4 x0 = xp[0], x1 = xp[1];
  float xv[8] = {x0.x, x0.y, x0.z, x0.w, x1.x, x1.y, x1.z, x1.w};
  float acc[16];
  #pragma unroll
  for (int h = 0; h < 16; ++h) acc[h] = b[h];
  #pragma unroll
  for (int f = 0; f < 8; ++f)
    #pragma unroll
    for (int h = 0; h < 16; ++h)
      acc[h] = fmaf(xv[f], w[f * 16 + h], acc[h]);
  int z = v % 12, y = (v / 12) % 24, xx = (v / 288) % 24, t = v / 6912;
  size_t pa = ((size_t)((t * 24 + xx) * 28 + y + 2) * 16 + z + 2) * 32;
  short8 o0, o1;
  #pragma unroll
  for (int h = 0; h < 8; ++h) { o0[h] = (short)f2bf(acc[h]); o1[h] = (short)f2bf(acc[8 + h]); }
  short8* op = reinterpret_cast<short8*>(act + pa);
  op[0] = o0; op[1] = o1;
}

// ---------------- weight -> B-fragment-ordered bf16 -----------------------
// wb[((q*NP + p)*NCOG + cog)*64 + lane], q=(dt*5+dx)*5+dy
// CIN16: k=g*8+j -> dz=2p+(g>>1), ci=(g&1)*8+j ; CIN32: ci=g*8+j, dz=p
template<int CIN, int COUT>
__global__ __launch_bounds__(256) void wtrans_mfma(
    const float* __restrict__ w, short8* __restrict__ wb) {
  constexpr int NP = (CIN == 16) ? 3 : 5;
  constexpr int NCOG = COUT / 16;
  int id = blockIdx.x * 256 + threadIdx.x;
  if (id >= 125 * NP * NCOG * 64) return;
  int lane = id & 63;
  int q = id >> 6;
  int cog = q % NCOG; q /= NCOG;
  int p = q % NP; q /= NP;            // q = (dt*5+dx)*5+dy
  int g = lane >> 4, n = lane & 15;
  int co = cog * 16 + n;
  short8 out;
  #pragma unroll
  for (int j = 0; j < 8; ++j) {
    int ci = (CIN == 16) ? ((g & 1) * 8 + j) : (g * 8 + j);
    int dz = (CIN == 16) ? (2 * p + (g >> 1)) : p;
    float val = 0.f;
    if (dz < 5) val = w[((size_t)co * CIN + ci) * 625 + q * 5 + dz];
    out[j] = (short)f2bf(val);
  }
  wb[id] = out;
}

// ---------------- conv4d via MFMA: 5-wave dt-split + LDS reduce -----------
template<int CIN, int COUT>
__global__ __launch_bounds__(320, 4) void conv4d_mfma(
    const unsigned short* __restrict__ act, const short8* __restrict__ wb,
    const float* __restrict__ bias, float* __restrict__ convout) {
  constexpr int NP = (CIN == 16) ? 3 : 5;
  constexpr int NCOG = COUT / 16;
  __shared__ float red[5][2 * NCOG][64][4];
  const int l = threadIdx.x & 63;
  const int dt = threadIdx.x >> 6;        // wave id = dt tap
  const int v0 = blockIdx.x * 32;
  const int col = l & 15, g = l >> 4;
  const int tsub = (CIN == 16) ? (g >> 1) : 0;
  const int c0 = (CIN == 16) ? ((g & 1) * 8) : (g * 8);
  const int t = v0 / 6912;                // uniform per block
  const int x = (v0 / 288) % 24;          // uniform per block

  floatx4 acc[2][NCOG];
  #pragma unroll
  for (int m = 0; m < 2; ++m)
    #pragma unroll
    for (int cg = 0; cg < NCOG; ++cg) acc[m][cg] = (floatx4){0.f, 0.f, 0.f, 0.f};

  const int ti = t + dt - 2;
  if ((unsigned)ti < (unsigned)TDIM) {
    const int y0 = ((v0 + col) / 12) % 24, z0 = (v0 + col) % 12;
    const int y1 = ((v0 + 16 + col) / 12) % 24, z1 = (v0 + 16 + col) % 12;
    for (int dx = 0; dx < 5; ++dx) {
      int xi = x + dx - 2;
      if ((unsigned)xi >= (unsigned)XDIM) continue;   // uniform skip
      int rowb = (ti * 24 + xi) * 28;
      // element offsets into padded act (dy advances by 512 elems = 1 py row)
      int b0 = ((rowb + y0) * 16 + z0 + tsub) * 32 + c0;
      int b1 = ((rowb + y1) * 16 + z1 + tsub) * 32 + c0;
      const short8* bp = wb + ((size_t)((dt * 5 + dx) * 5) * NP * NCOG) * 64 + l;
      #pragma unroll
      for (int dy = 0; dy < 5; ++dy) {
        short8 a0[NP], a1[NP], bf[NP][NCOG];
        #pragma unroll
        for (int p = 0; p < NP; ++p) {
          const int zo = (CIN == 16) ? p * 64 : p * 32;  // 2p or p z-steps
          a0[p] = *reinterpret_cast<const short8*>(act + b0 + zo);
          a1[p] = *reinterpret_cast<const short8*>(act + b1 + zo);
          #pragma unroll
          for (int cg = 0; cg < NCOG; ++cg)
            bf[p][cg] = bp[(dy * NP * NCOG + p * NCOG + cg) * 64];
        }
        #pragma unroll
        for (int p = 0; p < NP; ++p)
          #pragma unroll
          for (int cg = 0; cg < NCOG; ++cg) {
            acc[0][cg] = __builtin_amdgcn_mfma_f32_16x16x32_bf16(a0[p], bf[p][cg], acc[0][cg], 0, 0, 0);
            acc[1][cg] = __builtin_amdgcn_mfma_f32_16x16x32_bf16(a1[p], bf[p][cg], acc[1][cg], 0, 0, 0);
          }
        b0 += 512; b1 += 512;
      }
    }
  }
  // block reduce over the 5 dt-waves
  #pragma unroll
  for (int m = 0; m < 2; ++m)
    #pragma unroll
    for (int cg = 0; cg < NCOG; ++cg)
      #pragma unroll
      for (int i = 0; i < 4; ++i)
        red[dt][m * NCOG + cg][l][i] = acc[m][cg][i];
  __syncthreads();
  if (dt < 2 * NCOG) {
    const int m = dt / NCOG, cg = dt % NCOG;
    float s[4] = {0.f, 0.f, 0.f, 0.f};
    #pragma unroll
    for (int w = 0; w < 5; ++w)
      #pragma unroll
      for (int i = 0; i < 4; ++i) s[i] += red[w][dt][l][i];
    const int co = cg * 16 + col;
    const float bv = bias[co];
    #pragma unroll
    for (int i = 0; i < 4; ++i)
      convout[(size_t)(v0 + m * 16 + g * 4 + i) * COUT + co] = s[i] + bv;
  }
}

// ---------------- BN stats stage 1 ----------------------------------------
template<int C>
__global__ __launch_bounds__(256) void bn_stats1(
    const float* __restrict__ a, float* __restrict__ part) {
  int b = blockIdx.x, tt = threadIdx.x;
  const int chunk = (VOL / 256) * C;
  size_t base = (size_t)b * chunk;
  float s = 0.f, s2 = 0.f;
  for (int k = tt; k < chunk; k += 256) {
    float xv = a[base + k];
    s += xv; s2 = fmaf(xv, xv, s2);
  }
  __shared__ float shs[256], shs2[256];
  shs[tt] = s; shs2[tt] = s2;
  __syncthreads();
  if (tt < C) {
    float S = 0.f, S2 = 0.f;
    for (int j = tt; j < 256; j += C) { S += shs[j]; S2 += shs2[j]; }
    part[(size_t)(b * C + tt) * 2] = S;
    part[(size_t)(b * C + tt) * 2 + 1] = S2;
  }
}

// ---------------- BN stats stage 2: fold gamma/beta -----------------------
template<int C>
__global__ __launch_bounds__(64) void bn_stats2(
    const float* __restrict__ part, const float* __restrict__ gam,
    const float* __restrict__ bet, float* __restrict__ stats) {
  int c = threadIdx.x;
  if (c >= C) return;
  float S = 0.f, S2 = 0.f;
  for (int b = 0; b < 256; ++b) {
    S += part[(size_t)(b * C + c) * 2];
    S2 += part[(size_t)(b * C + c) * 2 + 1];
  }
  float mean = S * (1.f / VOL);
  float var = S2 * (1.f / VOL) - mean * mean;
  float sc = gam[c] * rsqrtf(var + EPSV);
  float sh = fmaf(-mean, sc, bet[c]);
  stats[2 * c] = sc;
  stats[2 * c + 1] = sh;
}

// ---------------- BN apply + LeakyReLU -> padded bf16 act -----------------
template<int C>
__global__ __launch_bounds__(256) void bn_apply(
    const float* __restrict__ a, const float* __restrict__ stats,
    unsigned short* __restrict__ act) {
  int i = blockIdx.x * 256 + threadIdx.x;     // covers VOL*C/8
  size_t e = (size_t)i * 8;
  int v = (int)(e / C);
  int cb = (int)(e & (C - 1));
  int z = v % 12, y = (v / 12) % 24, xx = (v / 288) % 24, t = v / 6912;
  size_t pa = ((size_t)((t * 24 + xx) * 28 + y + 2) * 16 + z + 2) * 32 + cb;
  const float4* p = reinterpret_cast<const float4*>(a + e);
  float4 f0 = p[0], f1 = p[1];
  float vv[8] = {f0.x, f0.y, f0.z, f0.w, f1.x, f1.y, f1.z, f1.w};
  short8 o;
  #pragma unroll
  for (int k = 0; k < 8; ++k) {
    float sc = stats[2 * (cb + k)], sh = stats[2 * (cb + k) + 1];
    float xv = fmaf(vv[k], sc, sh);
    xv = fmaxf(xv, SLOPE * xv);
    o[k] = (short)f2bf(xv);
  }
  *reinterpret_cast<short8*>(act + pa) = o;
}

// ---------------- projection ----------------------------------------------
__global__ __launch_bounds__(256) void proj_kernel(
    const unsigned short* __restrict__ act, const float* __restrict__ w,
    const float* __restrict__ b, float* __restrict__ out) {
  int v = blockIdx.x * 256 + threadIdx.x;
  int z = v % 12, y = (v / 12) % 24, xx = (v / 288) % 24, t = v / 6912;
  size_t pa = ((size_t)((t * 24 + xx) * 28 + y + 2) * 16 + z + 2) * 32;
  const short8* p = reinterpret_cast<const short8*>(act + pa);
  short8 a0 = p[0], a1 = p[1];
  float s = b[0];
  #pragma unroll
  for (int k = 0; k < 8; ++k) s = fmaf(bf2f((unsigned short)a0[k]), w[k], s);
  #pragma unroll
  for (int k = 0; k < 8; ++k) s = fmaf(bf2f((unsigned short)a1[k]), w[8 + k], s);
  out[v] = s;
}

extern "C" void kernel_launch(void* const* d_in, const int* in_sizes, int n_in,
                              void* d_out, int out_size, void* d_ws, size_t ws_size,
                              hipStream_t stream) {
  const float* x      = (const float*)d_in[0];
  const float* w_emb  = (const float*)d_in[1];
  const float* b_emb  = (const float*)d_in[2];
  const float* w1     = (const float*)d_in[3];
  const float* b1     = (const float*)d_in[4];
  const float* g1     = (const float*)d_in[5];
  const float* be1    = (const float*)d_in[6];
  const float* w2     = (const float*)d_in[7];
  const float* b2     = (const float*)d_in[8];
  const float* g2     = (const float*)d_in[9];
  const float* be2    = (const float*)d_in[10];
  const float* w3     = (const float*)d_in[11];
  const float* b3     = (const float*)d_in[12];
  const float* g3     = (const float*)d_in[13];
  const float* be3    = (const float*)d_in[14];
  const float* w_proj = (const float*)d_in[15];
  const float* b_proj = (const float*)d_in[16];

  char* ws = (char*)d_ws;
  unsigned short* ACT = (unsigned short*)(ws + ACT_OFF);
  float* CONV = (float*)(ws + CONV_OFF);
  short8* WB = (short8*)(ws + WB_OFF);
  float* STATS = (float*)(ws + STATS_OFF);
  float* PART = (float*)(ws + PART_OFF);
  float* out = (float*)d_out;

  zero_act<<<1024, 256, 0, stream>>>((float4*)ACT);   // 4 MiB incl. halo+slack
  embed_kernel<<<VOL / 256, 256, 0, stream>>>(x, w_emb, b_emb, ACT);

  // layer 1: 16 -> 16
  wtrans_mfma<16, 16><<<(125 * 3 * 1 * 64 + 255) / 256, 256, 0, stream>>>(w1, WB);
  conv4d_mfma<16, 16><<<VOL / 32, 320, 0, stream>>>(ACT, WB, b1, CONV);
  bn_stats1<16><<<256, 256, 0, stream>>>(CONV, PART);
  bn_stats2<16><<<1, 64, 0, stream>>>(PART, g1, be1, STATS);
  bn_apply<16><<<VOL * 16 / 2048, 256, 0, stream>>>(CONV, STATS, ACT);

  // layer 2: 16 -> 32
  wtrans_mfma<16, 32><<<(125 * 3 * 2 * 64 + 255) / 256, 256, 0, stream>>>(w2, WB);
  conv4d_mfma<16, 32><<<VOL / 32, 320, 0, stream>>>(ACT, WB, b2, CONV);
  bn_stats1<32><<<256, 256, 0, stream>>>(CONV, PART);
  bn_stats2<32><<<1, 64, 0, stream>>>(PART, g2, be2, STATS);
  bn_apply<32><<<VOL * 32 / 2048, 256, 0, stream>>>(CONV, STATS, ACT);

  // layer 3: 32 -> 16
  wtrans_mfma<32, 16><<<(125 * 5 * 1 * 64 + 255) / 256, 256, 0, stream>>>(w3, WB);
  conv4d_mfma<32, 16><<<VOL / 32, 320, 0, stream>>>(ACT, WB, b3, CONV);
  bn_stats1<16><<<256, 256, 0, stream>>>(CONV, PART);
  bn_stats2<16><<<1, 64, 0, stream>>>(PART, g3, be3, STATS);
  bn_apply<16><<<VOL * 16 / 2048, 256, 0, stream>>>(CONV, STATS, ACT);

  proj_kernel<<<VOL / 256, 256, 0, stream>>>(ACT, w_proj, b_proj, out);
}